// Round 5
// baseline (125.678 us; speedup 1.0000x reference)
//
#include <hip/hip_runtime.h>

#define NPIX (512*512)
#define CCH 32
#define KCL 16
#define BLKT 512
#define IMG_STRIDE 544      // per-image floats: [0..15]=cnt, [16]=wsum, [32..543]=sums[16][32]
#define LAB_OFF 8192        // float offset of packed u8 labels region in ws
#define WS_NEED ((LAB_OFF + NPIX * 8 / 4) * sizeof(float))

// reduce-scatter one level: keep lo/hi half by lane bit, exchange the other.
#define RS_LEVEL(ARR, HALF, MASK) { \
    const bool hi = (lane & (MASK)) != 0; \
    _Pragma("unroll") \
    for (int j = 0; j < (HALF); ++j) { \
      float send = hi ? ARR[j] : ARR[j + (HALF)]; \
      float recv = __shfl_xor(send, (MASK), 64); \
      ARR[j] = (hi ? ARR[j + (HALF)] : ARR[j]) + recv; \
    } }

// ---------------- prep: pack labels to u8 + per-image histogram ----------------
// 128 blocks = 8 images x 16 segments; 512 threads; 32 labels/thread.
__global__ void __launch_bounds__(512)
cl_prep_kernel(const int* __restrict__ labs, float* __restrict__ ws)
{
  const int b    = blockIdx.x >> 4;
  const int seg  = blockIdx.x & 15;
  const int tid  = threadIdx.x;
  const int lane = tid & 63;
  const int4* lb4 = reinterpret_cast<const int4*>(labs + b * NPIX + seg * (NPIX / 16));
  unsigned int* lab8 = reinterpret_cast<unsigned int*>(ws + LAB_OFF) +
                       (b * NPIX + seg * (NPIX / 16)) / 4;

  float c[KCL];
  #pragma unroll
  for (int k = 0; k < KCL; ++k) c[k] = 0.f;
  #pragma unroll
  for (int i = 0; i < 8; ++i) {
    const int4 v = lb4[tid + i * 512];
    lab8[tid + i * 512] = (unsigned int)(v.x & 15) | ((unsigned int)(v.y & 15) << 8) |
                          ((unsigned int)(v.z & 15) << 16) | ((unsigned int)(v.w & 15) << 24);
    #pragma unroll
    for (int k = 0; k < KCL; ++k) {
      c[k] += (v.x == k) ? 1.0f : 0.0f;
      c[k] += (v.y == k) ? 1.0f : 0.0f;
      c[k] += (v.z == k) ? 1.0f : 0.0f;
      c[k] += (v.w == k) ? 1.0f : 0.0f;
    }
  }
  RS_LEVEL(c, 8, 1)
  RS_LEVEL(c, 4, 2)
  RS_LEVEL(c, 2, 4)
  RS_LEVEL(c, 1, 8)
  c[0] += __shfl_xor(c[0], 16, 64);
  c[0] += __shfl_xor(c[0], 32, 64);
  if (lane < KCL) {
    const int v4 = (int)(__brev((unsigned)lane) >> 28);
    atomicAdd(&ws[b * IMG_STRIDE + v4], c[0]);
  }
}

// ---------------- accum: linear-stream kernel ----------------
// 512 blocks = 8 images x 32 channels x 2 halves; 512 threads = 8 waves.
// Block streams 512 KB of feats (fully linear) + 128 KB packed labels.
__global__ void __launch_bounds__(BLKT, 4)
cl_accum_lin(const float* __restrict__ feats, float* __restrict__ ws)
{
  const int idx  = blockIdx.x;
  const int b    = idx >> 6;
  const int c    = (idx >> 1) & 31;
  const int half = idx & 1;
  const int tid  = threadIdx.x;
  const int wave = tid >> 6;
  const int lane = tid & 63;

  const int px0 = half * (NPIX / 2);
  const float* fp = feats + ((long long)(b * CCH + c)) * NPIX + px0;
  const unsigned int* lp = reinterpret_cast<const unsigned int*>(
      reinterpret_cast<const unsigned char*>(ws + LAB_OFF) + b * NPIX + px0);

  // lane k<16 holds 1/cnt[k]; broadcast via shuffle in the loop
  const float vinv = 1.0f / ws[b * IMG_STRIDE + (lane & 15)];

  float acc[KCL];
  #pragma unroll
  for (int k = 0; k < KCL; ++k) acc[k] = 0.f;
  float wsum = 0.f;

  // 131072 px / 512 threads = 256 px/thread = 64 steps of 4 px
  #pragma unroll 4
  for (int s = 0; s < 64; ++s) {
    const int base = s * 2048 + tid * 4;
    const unsigned int lw = lp[base >> 2];
    const float4 v = *reinterpret_cast<const float4*>(fp + base);
    const float va[4] = {v.x, v.y, v.z, v.w};
    #pragma unroll
    for (int j = 0; j < 4; ++j) {
      const int lab = (int)((lw >> (8 * j)) & 0xFF);
      const float f = va[j];
      wsum = fmaf(__shfl(vinv, lab, 64), f * f, wsum);
      #pragma unroll
      for (int k = 0; k < KCL; ++k)
        acc[k] += (lab == k) ? f : 0.0f;
    }
  }

  // reduce acc[16] within wave: 4 RS levels + fold over lane bits 4,5
  RS_LEVEL(acc, 8, 1)
  RS_LEVEL(acc, 4, 2)
  RS_LEVEL(acc, 2, 4)
  RS_LEVEL(acc, 1, 8)
  acc[0] += __shfl_xor(acc[0], 16, 64);
  acc[0] += __shfl_xor(acc[0], 32, 64);
  #pragma unroll
  for (int mk = 1; mk < 64; mk <<= 1) wsum += __shfl_xor(wsum, mk, 64);

  __shared__ float hpart[8][KCL];
  __shared__ float swsum[8];
  if (lane < KCL) {
    const int v4 = (int)(__brev((unsigned)lane) >> 28);
    hpart[wave][v4] = acc[0];
  }
  if (lane == 0) swsum[wave] = wsum;
  __syncthreads();
  if (tid < KCL) {
    float t = 0.f;
    #pragma unroll
    for (int w = 0; w < 8; ++w) t += hpart[w][tid];
    atomicAdd(&ws[b * IMG_STRIDE + 32 + tid * 32 + c], t);
  }
  if (tid == KCL) {
    float t = 0.f;
    #pragma unroll
    for (int w = 0; w < 8; ++w) t += swsum[w];
    atomicAdd(&ws[b * IMG_STRIDE + 16], t);
  }
}

// ---------------- fallback accum (round-3 tile kernel, known good) ----------------
__global__ void __launch_bounds__(BLKT, 4)
cl_accum_fb(const float* __restrict__ feats, const int* __restrict__ labs,
            float* __restrict__ ws)
{
  const int b    = blockIdx.x >> 6;
  const int tile = blockIdx.x & 63;
  const int tid  = threadIdx.x;
  const int wave = tid >> 6;
  const int lane = tid & 63;
  const int px0  = tile * 4096;

  __shared__ unsigned char slab[4096];
  __shared__ float swei[4096];
  const int* lb = labs + b * NPIX + px0;
  const float* cntp = ws + b * IMG_STRIDE;
  #pragma unroll
  for (int i = 0; i < 8; ++i) {
    const int v = lb[tid + i * BLKT];
    slab[tid + i * BLKT] = (unsigned char)v;
    swei[tid + i * BLKT] = 1.0f / cntp[v];
  }
  __syncthreads();

  const float* fbase = feats + ((long long)b * CCH) * NPIX + px0;
  const float* f0 = fbase + (long long)(wave     ) * NPIX;
  const float* f1 = fbase + (long long)(wave +  8) * NPIX;
  const float* f2 = fbase + (long long)(wave + 16) * NPIX;
  const float* f3 = fbase + (long long)(wave + 24) * NPIX;

  float acc[4][KCL];
  #pragma unroll
  for (int ch = 0; ch < 4; ++ch)
    #pragma unroll
    for (int k = 0; k < KCL; ++k) acc[ch][k] = 0.f;
  float wsum = 0.f;

  #pragma unroll 2
  for (int s = 0; s < 16; ++s) {
    const int p = s * 256 + lane * 4;
    const unsigned int labw = *reinterpret_cast<const unsigned int*>(slab + p);
    const float4 w4 = *reinterpret_cast<const float4*>(swei + p);
    const float4 a0 = *reinterpret_cast<const float4*>(f0 + p);
    const float4 a1 = *reinterpret_cast<const float4*>(f1 + p);
    const float4 a2 = *reinterpret_cast<const float4*>(f2 + p);
    const float4 a3 = *reinterpret_cast<const float4*>(f3 + p);
    const float va0[4] = {a0.x, a0.y, a0.z, a0.w};
    const float va1[4] = {a1.x, a1.y, a1.z, a1.w};
    const float va2[4] = {a2.x, a2.y, a2.z, a2.w};
    const float va3[4] = {a3.x, a3.y, a3.z, a3.w};
    const float vw[4]  = {w4.x, w4.y, w4.z, w4.w};
    #pragma unroll
    for (int px = 0; px < 4; ++px) {
      const int lab = (int)((labw >> (8 * px)) & 0xFF);
      const float v0 = va0[px], v1 = va1[px], v2 = va2[px], v3 = va3[px];
      float sq = v0 * v0;
      sq = fmaf(v1, v1, sq);
      sq = fmaf(v2, v2, sq);
      sq = fmaf(v3, v3, sq);
      wsum = fmaf(vw[px], sq, wsum);
      #pragma unroll
      for (int k = 0; k < KCL; ++k) {
        const float m = (lab == k) ? 1.0f : 0.0f;
        acc[0][k] = fmaf(m, v0, acc[0][k]);
        acc[1][k] = fmaf(m, v1, acc[1][k]);
        acc[2][k] = fmaf(m, v2, acc[2][k]);
        acc[3][k] = fmaf(m, v3, acc[3][k]);
      }
    }
  }

  float a[64];
  #pragma unroll
  for (int ch = 0; ch < 4; ++ch)
    #pragma unroll
    for (int k = 0; k < KCL; ++k) a[ch * 16 + k] = acc[ch][k];

  RS_LEVEL(a, 32,  1)
  RS_LEVEL(a, 16,  2)
  RS_LEVEL(a,  8,  4)
  RS_LEVEL(a,  4,  8)
  RS_LEVEL(a,  2, 16)
  RS_LEVEL(a,  1, 32)

  {
    const int v6  = (int)(__brev((unsigned)lane) >> 26);
    const int chl = v6 >> 4, k = v6 & 15;
    const int c   = wave + chl * 8;
    atomicAdd(&ws[b * IMG_STRIDE + 32 + k * 32 + c], a[0]);
  }
  #pragma unroll
  for (int mk = 1; mk < 64; mk <<= 1) wsum += __shfl_xor(wsum, mk, 64);
  if (lane == 0) atomicAdd(&ws[b * IMG_STRIDE + 16], wsum);
}

// fallback hist (round-3, no packing)
__global__ void __launch_bounds__(512)
cl_hist_fb(const int* __restrict__ labs, float* __restrict__ ws)
{
  const int b    = blockIdx.x >> 4;
  const int seg  = blockIdx.x & 15;
  const int tid  = threadIdx.x;
  const int lane = tid & 63;
  const int* base = labs + b * NPIX + seg * (NPIX / 16);

  float c[KCL];
  #pragma unroll
  for (int k = 0; k < KCL; ++k) c[k] = 0.f;
  #pragma unroll 4
  for (int i = 0; i < 32; ++i) {
    const int v = base[tid + i * 512];
    #pragma unroll
    for (int k = 0; k < KCL; ++k) c[k] += (v == k) ? 1.0f : 0.0f;
  }
  RS_LEVEL(c, 8, 1)
  RS_LEVEL(c, 4, 2)
  RS_LEVEL(c, 2, 4)
  RS_LEVEL(c, 1, 8)
  c[0] += __shfl_xor(c[0], 16, 64);
  c[0] += __shfl_xor(c[0], 32, 64);
  if (lane < KCL) {
    const int v4 = (int)(__brev((unsigned)lane) >> 28);
    atomicAdd(&ws[b * IMG_STRIDE + v4], c[0]);
  }
}

// ---------------- finalize ----------------
__global__ void __launch_bounds__(512)
cl_finalize_kernel(const float* __restrict__ ws, float* __restrict__ out)
{
  __shared__ float smean[8][KCL][33];
  __shared__ float slossb[8];
  const int tid  = threadIdx.x;
  const int w    = tid >> 6;
  const int lane = tid & 63;
  const float* base = ws + w * IMG_STRIDE;

  float m2part = 0.f;
  #pragma unroll
  for (int j = 0; j < 8; ++j) {
    const int idx = lane * 8 + j;
    const int k = idx >> 5, c = idx & 31;
    const float m = base[32 + k * 32 + c] / base[k];
    smean[w][k][c] = m;
    m2part = fmaf(m, m, m2part);
  }
  float varp = -m2part;
  if (lane == 0) varp += base[16];
  #pragma unroll
  for (int mk = 1; mk < 64; mk <<= 1) varp += __shfl_xor(varp, mk, 64);

  __syncthreads();

  const int kk = lane >> 2, q = lane & 3;
  float n2 = 0.f;
  #pragma unroll
  for (int j = 0; j < 8; ++j) {
    const float m = smean[w][kk][q * 8 + j];
    n2 = fmaf(m, m, n2);
  }
  n2 += __shfl_xor(n2, 1, 64);
  n2 += __shfl_xor(n2, 2, 64);
  float regp = (q == 0) ? sqrtf(n2) : 0.f;
  #pragma unroll
  for (int mk = 1; mk < 64; mk <<= 1) regp += __shfl_xor(regp, mk, 64);

  float hing = 0.f;
  for (int p = lane; p < 120; p += 64) {
    int i = 0, rem = p;
    while (rem >= 15 - i) { rem -= 15 - i; ++i; }
    const int jj = i + 1 + rem;
    float d2 = 0.f;
    #pragma unroll
    for (int c = 0; c < 32; ++c) {
      const float d = smean[w][i][c] - smean[w][jj][c];
      d2 = fmaf(d, d, d2);
    }
    const float h = fmaxf(5.0f - sqrtf(d2), 0.f);
    hing = fmaf(h, h, hing);
  }
  #pragma unroll
  for (int mk = 1; mk < 64; mk <<= 1) hing += __shfl_xor(hing, mk, 64);

  if (lane == 0)
    slossb[w] = (varp + hing * (1.0f / 15.0f) + 0.005f * regp) * (1.0f / 16.0f);
  __syncthreads();
  if (tid == 0) {
    float t = 0.f;
    #pragma unroll
    for (int i = 0; i < 8; ++i) t += slossb[i];
    out[0] = t * (1.0f / 9.0f);
  }
}

extern "C" void kernel_launch(void* const* d_in, const int* in_sizes, int n_in,
                              void* d_out, int out_size, void* d_ws, size_t ws_size,
                              hipStream_t stream)
{
  const float* feats = (const float*)d_in[0];
  const int*   labs  = (const int*)d_in[1];
  float* out = (float*)d_out;
  float* ws  = (float*)d_ws;

  hipMemsetAsync(d_ws, 0, 8 * IMG_STRIDE * sizeof(float), stream);
  if (ws_size >= WS_NEED) {
    // linear-streaming path
    hipLaunchKernelGGL(cl_prep_kernel, dim3(128), dim3(512), 0, stream, labs, ws);
    hipLaunchKernelGGL(cl_accum_lin, dim3(512), dim3(BLKT), 0, stream, feats, ws);
  } else {
    // round-3 fallback
    hipLaunchKernelGGL(cl_hist_fb, dim3(128), dim3(512), 0, stream, labs, ws);
    hipLaunchKernelGGL(cl_accum_fb, dim3(512), dim3(BLKT), 0, stream, feats, labs, ws);
  }
  hipLaunchKernelGGL(cl_finalize_kernel, dim3(1), dim3(512), 0, stream, ws, out);
}